// Round 3
// baseline (593.094 us; speedup 1.0000x reference)
//
#include <hip/hip_runtime.h>
#include <math.h>

#define R2 2500.0f
#define EPSF 1e-8f

constexpr int H   = 256;   // feature dim (fixed by problem)
constexpr int HH  = 128;   // hidden dim
constexpr int NB  = 8;     // col-buckets per row (bucket = col>>11 -> 2048 nodes = 2MB of x)
constexpr int BSH = 11;    // bucket shift
constexpr int RPW = 8;     // rows per wave in k_fvar

// ---------------- K1: degree count per (row, bucket) ----------------
__global__ void k_degree(const int* __restrict__ row, const int* __restrict__ col,
                         int* __restrict__ deg4, int E) {
    int e = blockIdx.x * blockDim.x + threadIdx.x;
    if (e < E) atomicAdd(&deg4[row[e] * NB + (col[e] >> BSH)], 1);
}

// ---------------- K2: exclusive scan over M=N*NB (single block) ----------------
// Writes rp4 (offsets) and cur4 (running-cursor copy for k_fill, avoids a
// second zeroed array + rp4 reads in fill). Two-pass over deg4 (L2-hot)
// instead of a per-thread vals[] array (would need 128 VGPRs).
__global__ void k_scan(const int* __restrict__ deg4, int* __restrict__ rp4,
                       int* __restrict__ cur4, int M) {
    __shared__ int s[1024];
    int t = threadIdx.x;
    int per = M >> 10;            // 128
    int base = t * per;
    int local = 0;
    for (int k = 0; k < per; k++) local += deg4[base + k];
    s[t] = local;
    __syncthreads();
    for (int off = 1; off < 1024; off <<= 1) {
        int v = s[t];
        int add = (t >= off) ? s[t - off] : 0;
        __syncthreads();
        s[t] = v + add;
        __syncthreads();
    }
    int excl = (t > 0) ? s[t - 1] : 0;
    for (int k = 0; k < per; k++) {
        int v = deg4[base + k];
        rp4[base + k]  = excl;
        cur4[base + k] = excl;
        excl += v;
    }
    if (t == 1023) rp4[M] = excl;
}

// ---------------- K3: fill bucket-sorted CSR ----------------
__global__ void k_fill(const int* __restrict__ row, const int* __restrict__ col,
                       int* __restrict__ cur4, int* __restrict__ cols, int E) {
    int e = blockIdx.x * blockDim.x + threadIdx.x;
    if (e < E) {
        int r = row[e], c = col[e];
        int p = atomicAdd(&cur4[r * NB + (c >> BSH)], 1);
        cols[p] = c;
    }
}

// ---------------- K4a: pack per-j point data (x, y, |c|^2, pad) ----------------
__global__ void k_prep(const float* __restrict__ coords, float4* __restrict__ pj, int N) {
    int i = blockIdx.x * 256 + threadIdx.x;
    if (i < N) {
        float2 c = ((const float2*)coords)[i];
        pj[i] = make_float4(c.x, c.y, c.x * c.x + c.y * c.y, 0.0f);
    }
}

// ---------------- K4: spatial density — SGPR-broadcast N-body ----------------
__global__ void __launch_bounds__(256) k_density(
    const float* __restrict__ coords, const float4* __restrict__ pj,
    int* __restrict__ dens, int N, int jPer) {
    int i = blockIdx.x * 256 + threadIdx.x;
    const float2* c2 = (const float2*)coords;
    float2 ci = c2[i];
    float sqi = ci.x * ci.x + ci.y * ci.y;
    int j0 = blockIdx.y * jPer;
    int cnt = 0;
#pragma unroll 8
    for (int j = j0; j < j0 + jPer; j++) {
        float4 q = pj[j];                      // uniform addr -> scalar path
        float dot = ci.x * q.x + ci.y * q.y;
        float d2 = (sqi + q.z) - 2.0f * dot;
        cnt += (d2 <= R2) ? 1 : 0;
    }
    atomicAdd(&dens[i], cnt);
}

// ---------------- K5: fvar — bucket-major synchronized sweep ----------------
// Each wave owns RPW=8 rows (acc in 32 statically-indexed VGPRs), iterates
// col-buckets OUTERMOST. Grid = N/(4*RPW) = 512 blocks = 2/CU -> all blocks
// resident from t=0, so every wave reads the same ~2MB bucket window of x at
// the same time -> x stays L2-resident; compulsory L2 miss ~16MB/XCD/sweep.
// Gather itself is R1's proven structure: 8 async global_load_lds (1KB row
// each), one drain, accumulate from LDS.
__global__ void __launch_bounds__(256) k_fvar(
    const float* __restrict__ x, const int* __restrict__ rp4,
    const int* __restrict__ cols, float* __restrict__ fvar, int N) {
    __shared__ float4 lds[4][8][64];   // 4 waves x 8 slots x 1KB = 32KB
    int wave = threadIdx.x >> 6;
    int lane = threadIdx.x & 63;
    int i0 = (blockIdx.x * 4 + wave) * RPW;
    const float4* xb = (const float4*)x;   // 64 float4 per row
    float4 acc[RPW];
#pragma unroll
    for (int r = 0; r < RPW; r++) acc[r] = make_float4(0.f, 0.f, 0.f, 0.f);

    for (int b = 0; b < NB; b++) {
#pragma unroll
        for (int r = 0; r < RPW; r++) {
            int s = rp4[(i0 + r) * NB + b];
            int e = rp4[(i0 + r) * NB + b + 1];
            for (int p0 = s; p0 < e; p0 += 64) {
                int m = e - p0; if (m > 64) m = 64;
                int idx = cols[p0 + (lane < m ? lane : m - 1)];
                for (int j = 0; j < m; j += 8) {
                    int nb2 = m - j; if (nb2 > 8) nb2 = 8;
#pragma unroll
                    for (int k = 0; k < 8; k++) {
                        if (k < nb2) {
                            int c = __shfl(idx, j + k, 64);
                            const float4* gp = xb + (size_t)c * 64 + lane;
                            __builtin_amdgcn_global_load_lds(
                                (const __attribute__((address_space(1))) void*)gp,
                                (__attribute__((address_space(3))) void*)(&lds[wave][k][0]),
                                16, 0, 0);
                        }
                    }
                    __builtin_amdgcn_s_waitcnt(0);   // drain the async row fetches
#pragma unroll
                    for (int k = 0; k < 8; k++) {
                        if (k < nb2) {
                            float4 v = lds[wave][k][lane];
                            acc[r].x += v.x; acc[r].y += v.y;
                            acc[r].z += v.z; acc[r].w += v.w;
                        }
                    }
                }
            }
        }
    }

#pragma unroll
    for (int r = 0; r < RPW; r++) {
        int i = i0 + r;
        float cnt = fmaxf((float)(rp4[(i + 1) * NB] - rp4[i * NB]), 1.0f);
        float4 xi = xb[(size_t)i * 64 + lane];
        float dx = xi.x - acc[r].x / cnt;
        float dy = xi.y - acc[r].y / cnt;
        float dz = xi.z - acc[r].z / cnt;
        float dw = xi.w - acc[r].w / cnt;
        float ss = dx * dx + dy * dy + dz * dz + dw * dw;
#pragma unroll
        for (int off = 32; off > 0; off >>= 1) ss += __shfl_xor(ss, off, 64);
        if (lane == 0) fvar[i] = sqrtf(ss);
    }
}

// ---------------- K5b: maxima reduction (deg, dens, fvar) ----------------
__global__ void __launch_bounds__(256) k_scal(
    const int* __restrict__ rp4, const int* __restrict__ dens,
    const float* __restrict__ fvar, int* __restrict__ scal, int N) {
    __shared__ int sd[4], sn[4];
    __shared__ float sf[4];
    int t = threadIdx.x;
    int g = blockIdx.x * 256 + t;
    int stride = 256 * gridDim.x;
    int md = 0, mn = 0;
    float mf = 0.f;
    for (int i = g; i < N; i += stride) {
        md = max(md, rp4[(i + 1) * NB] - rp4[i * NB]);
        mn = max(mn, dens[i]);
        mf = fmaxf(mf, fvar[i]);
    }
#pragma unroll
    for (int off = 32; off > 0; off >>= 1) {
        md = max(md, __shfl_xor(md, off, 64));
        mn = max(mn, __shfl_xor(mn, off, 64));
        mf = fmaxf(mf, __shfl_xor(mf, off, 64));
    }
    int w = t >> 6, l = t & 63;
    if (l == 0) { sd[w] = md; sn[w] = mn; sf[w] = mf; }
    __syncthreads();
    if (t == 0) {
#pragma unroll
        for (int k = 1; k < 4; k++) {
            md = max(md, sd[k]);
            mn = max(mn, sn[k]);
            mf = fmaxf(mf, sf[k]);
        }
        atomicMax(&scal[0], md);
        atomicMax(&scal[1], mn);
        atomicMax(&scal[2], __float_as_int(mf));   // nonneg float: int-max ok
    }
}

// ---------------- K6: tiny MLP ----------------
__global__ void __launch_bounds__(256) k_mlp(
    const float* __restrict__ w1, const float* __restrict__ b1,
    const float* __restrict__ w2, const float* __restrict__ b2,
    const int* __restrict__ rp4, const int* __restrict__ dens,
    const float* __restrict__ fvar, const int* __restrict__ scal,
    float* __restrict__ out, int N) {
    __shared__ float sh_h[HH];
    int j = threadIdx.x;
    float wv[HH];
#pragma unroll
    for (int l = 0; l < HH; l++) wv[l] = w2[l * H + j];
    float bj = b2[j];
    float maxdeg  = (float)scal[0] + EPSF;
    float maxdens = (float)(scal[1] - 1) + EPSF;
    float maxfv   = __int_as_float(scal[2]) + EPSF;
    float w1a = 0.f, w1b = 0.f, w1c = 0.f, b1j = 0.f;
    if (j < HH) { w1a = w1[j]; w1b = w1[HH + j]; w1c = w1[2 * HH + j]; b1j = b1[j]; }
    for (int i = blockIdx.x; i < N; i += gridDim.x) {
        float f0 = (float)(rp4[(i + 1) * NB] - rp4[i * NB]) / maxdeg;
        float f1 = (float)(dens[i] - 1) / maxdens;
        float f2 = fvar[i] / maxfv;
        if (j < HH) {
            float h = f0 * w1a + f1 * w1b + f2 * w1c + b1j;
            sh_h[j] = fmaxf(h, 0.0f);
        }
        __syncthreads();
        float acc = bj;
#pragma unroll
        for (int l = 0; l < HH; l++) acc = fmaf(sh_h[l], wv[l], acc);
        out[(size_t)i * H + j] = acc;
        __syncthreads();
    }
}

extern "C" void kernel_launch(void* const* d_in, const int* in_sizes, int n_in,
                              void* d_out, int out_size, void* d_ws, size_t ws_size,
                              hipStream_t stream) {
    const float* x      = (const float*)d_in[0];
    const int*   ei     = (const int*)d_in[1];
    const float* coords = (const float*)d_in[2];
    const float* w1     = (const float*)d_in[3];
    const float* b1     = (const float*)d_in[4];
    const float* w2     = (const float*)d_in[5];
    const float* b2     = (const float*)d_in[6];
    float* out = (float*)d_out;

    const int N = in_sizes[2] / 2;   // 16384
    const int E = in_sizes[1] / 2;   // 524288
    const int M = N * NB;            // 131072
    const int* row = ei;
    const int* col = ei + E;

    // workspace layout (int32 elements)
    int* ws       = (int*)d_ws;
    int* dens_cnt = ws;                        // [N]    zeroed
    int* scal     = ws + N;                    // [4]    zeroed
    int* deg4     = ws + N + 4;                // [M]    zeroed
    int* rp4      = ws + N + 4 + M;            // [M+1]
    int* cur4     = ws + N + 4 + 2 * M + 1;    // [M]
    float* fvarp  = (float*)(ws + N + 4 + 3 * M + 1);  // [N]
    int* cols     = ws + 2 * N + 4 + 3 * M + 1;        // [E]
    float4* pj    = (float4*)(ws + ((2 * N + 4 + 3 * M + 1 + E + 3) & ~3)); // [N]

    hipMemsetAsync(ws, 0, (size_t)(N + 4 + M) * sizeof(int), stream);

    int eb = (E + 255) / 256;
    k_degree<<<eb, 256, 0, stream>>>(row, col, deg4, E);
    k_scan<<<1, 1024, 0, stream>>>(deg4, rp4, cur4, M);
    k_fill<<<eb, 256, 0, stream>>>(row, col, cur4, cols, E);

    k_prep<<<N / 256, 256, 0, stream>>>(coords, pj, N);
    const int NSLICE = 16;
    k_density<<<dim3(N / 256, NSLICE), 256, 0, stream>>>(coords, pj, dens_cnt, N, N / NSLICE);

    k_fvar<<<N / (4 * RPW), 256, 0, stream>>>(x, rp4, cols, fvarp, N);

    k_scal<<<64, 256, 0, stream>>>(rp4, dens_cnt, fvarp, scal, N);

    k_mlp<<<1024, 256, 0, stream>>>(w1, b1, w2, b2, rp4, dens_cnt, fvarp, scal,
                                    out, N);
}

// Round 4
// 314.625 us; speedup vs baseline: 1.8851x; 1.8851x over previous
//
#include <hip/hip_runtime.h>
#include <math.h>

#define R2 2500.0f
#define EPSF 1e-8f

constexpr int H   = 256;   // feature dim (fixed by problem)
constexpr int HH  = 128;   // hidden dim
constexpr int NB  = 8;     // col-buckets per row (bucket = col>>11 -> 2048 nodes = 2MB of x)
constexpr int BSH = 11;    // bucket shift
constexpr int RPW = 8;     // rows per wave in k_fvar

// ---------------- K1: degree count per (row, bucket) ----------------
__global__ void k_degree(const int* __restrict__ row, const int* __restrict__ col,
                         int* __restrict__ deg4, int E) {
    int e = blockIdx.x * blockDim.x + threadIdx.x;
    if (e < E) atomicAdd(&deg4[row[e] * NB + (col[e] >> BSH)], 1);
}

// ---------------- K2: parallel exclusive scan over M=N*NB ----------------
// 3-stage block-sums hierarchy; each stage is launch-bound (~2-3us).
// K2a: per-block sums (M/1024 = 128 blocks x 256 thr, int4/thread)
__global__ void __launch_bounds__(256) k_bsum(const int* __restrict__ deg4,
                                              int* __restrict__ bsum) {
    int t = threadIdx.x;
    int4 v = ((const int4*)deg4)[blockIdx.x * 256 + t];
    int sum = v.x + v.y + v.z + v.w;
#pragma unroll
    for (int off = 32; off > 0; off >>= 1) sum += __shfl_xor(sum, off, 64);
    __shared__ int sw[4];
    if ((t & 63) == 0) sw[t >> 6] = sum;
    __syncthreads();
    if (t == 0) bsum[blockIdx.x] = sw[0] + sw[1] + sw[2] + sw[3];
}

// K2b: exclusive scan of the 128 block sums (1 block x 128 thr)
__global__ void k_bscan(const int* __restrict__ bsum, int* __restrict__ boff) {
    __shared__ int s[128];
    int t = threadIdx.x;
    s[t] = bsum[t];
    __syncthreads();
    for (int off = 1; off < 128; off <<= 1) {
        int v = s[t];
        int add = (t >= off) ? s[t - off] : 0;
        __syncthreads();
        s[t] = v + add;
        __syncthreads();
    }
    boff[t] = (t > 0) ? s[t - 1] : 0;
}

// K2c: block-local scan + global offset -> rp4, cur4 (int4 stores)
__global__ void __launch_bounds__(256) k_scat(const int* __restrict__ deg4,
                                              const int* __restrict__ boff,
                                              int* __restrict__ rp4,
                                              int* __restrict__ cur4, int M) {
    int t = threadIdx.x, blk = blockIdx.x;
    int lane = t & 63, w = t >> 6;
    int4 v = ((const int4*)deg4)[blk * 256 + t];
    int tsum = v.x + v.y + v.z + v.w;
    int incl = tsum;
#pragma unroll
    for (int off = 1; off < 64; off <<= 1) {
        int n = __shfl_up(incl, off, 64);
        if (lane >= off) incl += n;
    }
    __shared__ int wsum[4];
    if (lane == 63) wsum[w] = incl;
    __syncthreads();
    int woff = 0;
#pragma unroll
    for (int k = 0; k < 4; k++) woff += (k < w) ? wsum[k] : 0;
    int excl = boff[blk] + woff + (incl - tsum);
    int4 r;
    r.x = excl;
    r.y = excl + v.x;
    r.z = excl + v.x + v.y;
    r.w = excl + v.x + v.y + v.z;
    ((int4*)rp4)[blk * 256 + t]  = r;
    ((int4*)cur4)[blk * 256 + t] = r;
    if (blk == gridDim.x - 1 && t == 255) rp4[M] = excl + tsum;
}

// ---------------- K3: fill bucket-sorted CSR ----------------
__global__ void k_fill(const int* __restrict__ row, const int* __restrict__ col,
                       int* __restrict__ cur4, int* __restrict__ cols, int E) {
    int e = blockIdx.x * blockDim.x + threadIdx.x;
    if (e < E) {
        int r = row[e], c = col[e];
        int p = atomicAdd(&cur4[r * NB + (c >> BSH)], 1);
        cols[p] = c;
    }
}

// ---------------- K4a: pack per-j point data (x, y, |c|^2, pad) ----------------
__global__ void k_prep(const float* __restrict__ coords, float4* __restrict__ pj, int N) {
    int i = blockIdx.x * 256 + threadIdx.x;
    if (i < N) {
        float2 c = ((const float2*)coords)[i];
        pj[i] = make_float4(c.x, c.y, c.x * c.x + c.y * c.y, 0.0f);
    }
}

// ---------------- K4: spatial density — SGPR-broadcast N-body ----------------
__global__ void __launch_bounds__(256) k_density(
    const float* __restrict__ coords, const float4* __restrict__ pj,
    int* __restrict__ dens, int N, int jPer) {
    int i = blockIdx.x * 256 + threadIdx.x;
    const float2* c2 = (const float2*)coords;
    float2 ci = c2[i];
    float sqi = ci.x * ci.x + ci.y * ci.y;
    int j0 = blockIdx.y * jPer;
    int cnt = 0;
#pragma unroll 8
    for (int j = j0; j < j0 + jPer; j++) {
        float4 q = pj[j];                      // uniform addr -> scalar path
        float dot = ci.x * q.x + ci.y * q.y;
        float d2 = (sqi + q.z) - 2.0f * dot;
        cnt += (d2 <= R2) ? 1 : 0;
    }
    atomicAdd(&dens[i], cnt);
}

// ---------------- K5: fvar — bucket-major synchronized sweep ----------------
// Each wave owns RPW=8 rows (acc in 32 statically-indexed VGPRs), iterates
// col-buckets OUTERMOST. Grid = N/(4*RPW) = 512 blocks = 2/CU -> all blocks
// resident from t=0, so every wave reads the same ~2MB bucket window of x at
// the same time -> x stays L2-resident; compulsory L2 miss ~16MB/XCD/sweep.
__global__ void __launch_bounds__(256) k_fvar(
    const float* __restrict__ x, const int* __restrict__ rp4,
    const int* __restrict__ cols, float* __restrict__ fvar, int N) {
    __shared__ float4 lds[4][8][64];   // 4 waves x 8 slots x 1KB = 32KB
    int wave = threadIdx.x >> 6;
    int lane = threadIdx.x & 63;
    int i0 = (blockIdx.x * 4 + wave) * RPW;
    const float4* xb = (const float4*)x;   // 64 float4 per row
    float4 acc[RPW];
#pragma unroll
    for (int r = 0; r < RPW; r++) acc[r] = make_float4(0.f, 0.f, 0.f, 0.f);

    for (int b = 0; b < NB; b++) {
#pragma unroll
        for (int r = 0; r < RPW; r++) {
            int s = rp4[(i0 + r) * NB + b];
            int e = rp4[(i0 + r) * NB + b + 1];
            for (int p0 = s; p0 < e; p0 += 64) {
                int m = e - p0; if (m > 64) m = 64;
                int idx = cols[p0 + (lane < m ? lane : m - 1)];
                for (int j = 0; j < m; j += 8) {
                    int nb2 = m - j; if (nb2 > 8) nb2 = 8;
#pragma unroll
                    for (int k = 0; k < 8; k++) {
                        if (k < nb2) {
                            int c = __shfl(idx, j + k, 64);
                            const float4* gp = xb + (size_t)c * 64 + lane;
                            __builtin_amdgcn_global_load_lds(
                                (const __attribute__((address_space(1))) void*)gp,
                                (__attribute__((address_space(3))) void*)(&lds[wave][k][0]),
                                16, 0, 0);
                        }
                    }
                    __builtin_amdgcn_s_waitcnt(0);   // drain the async row fetches
#pragma unroll
                    for (int k = 0; k < 8; k++) {
                        if (k < nb2) {
                            float4 v = lds[wave][k][lane];
                            acc[r].x += v.x; acc[r].y += v.y;
                            acc[r].z += v.z; acc[r].w += v.w;
                        }
                    }
                }
            }
        }
    }

#pragma unroll
    for (int r = 0; r < RPW; r++) {
        int i = i0 + r;
        float cnt = fmaxf((float)(rp4[(i + 1) * NB] - rp4[i * NB]), 1.0f);
        float4 xi = xb[(size_t)i * 64 + lane];
        float dx = xi.x - acc[r].x / cnt;
        float dy = xi.y - acc[r].y / cnt;
        float dz = xi.z - acc[r].z / cnt;
        float dw = xi.w - acc[r].w / cnt;
        float ss = dx * dx + dy * dy + dz * dz + dw * dw;
#pragma unroll
        for (int off = 32; off > 0; off >>= 1) ss += __shfl_xor(ss, off, 64);
        if (lane == 0) fvar[i] = sqrtf(ss);
    }
}

// ---------------- K5b: maxima reduction (deg, dens, fvar) ----------------
__global__ void __launch_bounds__(256) k_scal(
    const int* __restrict__ rp4, const int* __restrict__ dens,
    const float* __restrict__ fvar, int* __restrict__ scal, int N) {
    __shared__ int sd[4], sn[4];
    __shared__ float sf[4];
    int t = threadIdx.x;
    int g = blockIdx.x * 256 + t;
    int stride = 256 * gridDim.x;
    int md = 0, mn = 0;
    float mf = 0.f;
    for (int i = g; i < N; i += stride) {
        md = max(md, rp4[(i + 1) * NB] - rp4[i * NB]);
        mn = max(mn, dens[i]);
        mf = fmaxf(mf, fvar[i]);
    }
#pragma unroll
    for (int off = 32; off > 0; off >>= 1) {
        md = max(md, __shfl_xor(md, off, 64));
        mn = max(mn, __shfl_xor(mn, off, 64));
        mf = fmaxf(mf, __shfl_xor(mf, off, 64));
    }
    int w = t >> 6, l = t & 63;
    if (l == 0) { sd[w] = md; sn[w] = mn; sf[w] = mf; }
    __syncthreads();
    if (t == 0) {
#pragma unroll
        for (int k = 1; k < 4; k++) {
            md = max(md, sd[k]);
            mn = max(mn, sn[k]);
            mf = fmaxf(mf, sf[k]);
        }
        atomicMax(&scal[0], md);
        atomicMax(&scal[1], mn);
        atomicMax(&scal[2], __float_as_int(mf));   // nonneg float: int-max ok
    }
}

// ---------------- K6: tiny MLP ----------------
__global__ void __launch_bounds__(256) k_mlp(
    const float* __restrict__ w1, const float* __restrict__ b1,
    const float* __restrict__ w2, const float* __restrict__ b2,
    const int* __restrict__ rp4, const int* __restrict__ dens,
    const float* __restrict__ fvar, const int* __restrict__ scal,
    float* __restrict__ out, int N) {
    __shared__ float sh_h[HH];
    int j = threadIdx.x;
    float wv[HH];
#pragma unroll
    for (int l = 0; l < HH; l++) wv[l] = w2[l * H + j];
    float bj = b2[j];
    float maxdeg  = (float)scal[0] + EPSF;
    float maxdens = (float)(scal[1] - 1) + EPSF;
    float maxfv   = __int_as_float(scal[2]) + EPSF;
    float w1a = 0.f, w1b = 0.f, w1c = 0.f, b1j = 0.f;
    if (j < HH) { w1a = w1[j]; w1b = w1[HH + j]; w1c = w1[2 * HH + j]; b1j = b1[j]; }
    for (int i = blockIdx.x; i < N; i += gridDim.x) {
        float f0 = (float)(rp4[(i + 1) * NB] - rp4[i * NB]) / maxdeg;
        float f1 = (float)(dens[i] - 1) / maxdens;
        float f2 = fvar[i] / maxfv;
        if (j < HH) {
            float h = f0 * w1a + f1 * w1b + f2 * w1c + b1j;
            sh_h[j] = fmaxf(h, 0.0f);
        }
        __syncthreads();
        float acc = bj;
#pragma unroll
        for (int l = 0; l < HH; l++) acc = fmaf(sh_h[l], wv[l], acc);
        out[(size_t)i * H + j] = acc;
        __syncthreads();
    }
}

extern "C" void kernel_launch(void* const* d_in, const int* in_sizes, int n_in,
                              void* d_out, int out_size, void* d_ws, size_t ws_size,
                              hipStream_t stream) {
    const float* x      = (const float*)d_in[0];
    const int*   ei     = (const int*)d_in[1];
    const float* coords = (const float*)d_in[2];
    const float* w1     = (const float*)d_in[3];
    const float* b1     = (const float*)d_in[4];
    const float* w2     = (const float*)d_in[5];
    const float* b2     = (const float*)d_in[6];
    float* out = (float*)d_out;

    const int N = in_sizes[2] / 2;   // 16384
    const int E = in_sizes[1] / 2;   // 524288
    const int M = N * NB;            // 131072
    const int NBLK = M / 1024;       // 128 scan blocks
    const int* row = ei;
    const int* col = ei + E;

    // workspace layout (int32 elements; keep int4-stored arrays 16B-aligned)
    int* ws       = (int*)d_ws;
    int* dens_cnt = ws;                        // [N]    zeroed
    int* scal     = ws + N;                    // [4]    zeroed
    int* deg4     = ws + N + 4;                // [M]    zeroed   (16B-aligned)
    int* rp4      = ws + N + 4 + M;            // [M+4]           (16B-aligned)
    int* cur4     = ws + N + 8 + 2 * M;        // [M]             (16B-aligned)
    float* fvarp  = (float*)(ws + N + 8 + 3 * M);      // [N]
    int* cols     = ws + 2 * N + 8 + 3 * M;            // [E]
    int* bsum     = ws + 2 * N + 8 + 3 * M + E;        // [128]
    int* boff     = bsum + 128;                        // [128]
    float4* pj    = (float4*)(ws + ((2 * N + 8 + 3 * M + E + 256 + 3) & ~3)); // [N]

    hipMemsetAsync(ws, 0, (size_t)(N + 4 + M) * sizeof(int), stream);

    int eb = (E + 255) / 256;
    k_degree<<<eb, 256, 0, stream>>>(row, col, deg4, E);
    k_bsum<<<NBLK, 256, 0, stream>>>(deg4, bsum);
    k_bscan<<<1, NBLK, 0, stream>>>(bsum, boff);
    k_scat<<<NBLK, 256, 0, stream>>>(deg4, boff, rp4, cur4, M);
    k_fill<<<eb, 256, 0, stream>>>(row, col, cur4, cols, E);

    k_prep<<<N / 256, 256, 0, stream>>>(coords, pj, N);
    const int NSLICE = 16;
    k_density<<<dim3(N / 256, NSLICE), 256, 0, stream>>>(coords, pj, dens_cnt, N, N / NSLICE);

    k_fvar<<<N / (4 * RPW), 256, 0, stream>>>(x, rp4, cols, fvarp, N);

    k_scal<<<64, 256, 0, stream>>>(rp4, dens_cnt, fvarp, scal, N);

    k_mlp<<<1024, 256, 0, stream>>>(w1, b1, w2, b2, rp4, dens_cnt, fvarp, scal,
                                    out, N);
}